// Round 8
// baseline (479.261 us; speedup 1.0000x reference)
//
#include <hip/hip_runtime.h>

typedef unsigned short u16;
typedef unsigned int u32;
typedef __attribute__((ext_vector_type(8))) short bf16x8;
typedef __attribute__((ext_vector_type(4))) float f32x4;
typedef __attribute__((ext_vector_type(16))) float f32x16;

#define NB 16
#define NC 256
#define NL 2048
#define NG 32
#define CPG 8
#define GN_N (CPG * NL)
#define EPS 1e-5f
#define QSC2 0.0901684401f   // (1/sqrt(256)) * log2(e): S emerges in log2 domain
#define DEFER 11.54f         // 8 * log2(e)
#define TROWS 2050           // 2048 + 2 zero pad rows (l = row-1)
#define PHALF ((size_t)NB * NC * NL)

__device__ __forceinline__ float bf2f(u16 a) {
  union { unsigned u; float f; } v; v.u = (unsigned)a << 16; return v.f;
}
__device__ __forceinline__ u16 f2bf(float f) {
  union { float f; unsigned u; } v; v.f = f;
  return (u16)((v.u + 0x7fffu + ((v.u >> 16) & 1u)) >> 16);
}
__device__ __forceinline__ u32 cvtpk(float lo, float hi) {
  u32 r;
  asm("v_cvt_pk_bf16_f32 %0, %1, %2" : "=v"(r) : "v"(lo), "v"(hi));
  return r;
}
__device__ __forceinline__ float ex2(float x) {
  float r;
  asm("v_exp_f32 %0, %1" : "=v"(r) : "v"(x));   // D = 2^S0
  return r;
}
__device__ __forceinline__ void gld16(const void* gsrc, void* ldst) {
  __builtin_amdgcn_global_load_lds(
      (const __attribute__((address_space(1))) void*)gsrc,
      (__attribute__((address_space(3))) void*)ldst, 16, 0, 0);
}

// ---------------- weight pack ----------------
__global__ __launch_bounds__(256)
void pack_w(const float* __restrict__ w1, const float* __restrict__ w2,
            const float* __restrict__ w3, const float* __restrict__ w4,
            const float* __restrict__ lw, const float* __restrict__ lb,
            u16* __restrict__ Wp, u16* __restrict__ Wq, float* __restrict__ bq)
{
  const int a = blockIdx.y;
  const int gid = blockIdx.x * 256 + threadIdx.x;   // < 196608
  if (a < 4) {
    const float* w = a == 0 ? w1 : a == 1 ? w2 : a == 2 ? w3 : w4;
    const int d = gid >> 16, rem = gid & 65535;
    const int oc = rem >> 8, ic = rem & 255;
    Wp[a * 196608 + gid] = f2bf(w[(oc * 256 + ic) * 3 + d]);
  } else {
    const int oc = gid >> 8;
    const float s = (oc >= 256 && oc < 512) ? QSC2 : 1.0f;
    Wq[gid] = f2bf(lw[gid] * s);
    if (gid < 768) bq[gid] = lb[gid] * ((gid >= 256 && gid < 512) ? QSC2 : 1.0f);
  }
}

// ---------------- GroupNorm+ReLU: fp32 (B,C,L) -> bf16 T padded (B,2050,256) ----
__global__ __launch_bounds__(256)
void gn_f32_T(const float* __restrict__ x, const float* __restrict__ gw,
              const float* __restrict__ gb, u16* __restrict__ outT)
{
  const int b = blockIdx.x >> 5, g = blockIdx.x & 31;
  const float* xp = x + ((size_t)b * NC + g * CPG) * NL;
  float s = 0.f, ss = 0.f;
  for (int i = threadIdx.x; i < GN_N / 4; i += 256) {
    float4 v = ((const float4*)xp)[i];
    s += (v.x + v.y) + (v.z + v.w);
    ss += (v.x * v.x + v.y * v.y) + (v.z * v.z + v.w * v.w);
  }
#pragma unroll
  for (int o = 32; o > 0; o >>= 1) { s += __shfl_down(s, o); ss += __shfl_down(ss, o); }
  __shared__ float rs[4], rss[4], stat[2];
  if ((threadIdx.x & 63) == 0) { rs[threadIdx.x >> 6] = s; rss[threadIdx.x >> 6] = ss; }
  __syncthreads();
  if (threadIdx.x == 0) {
    float S = rs[0] + rs[1] + rs[2] + rs[3];
    float SS = rss[0] + rss[1] + rss[2] + rss[3];
    float mean = S * (1.f / GN_N);
    float var = SS * (1.f / GN_N) - mean * mean;
    stat[0] = mean; stat[1] = rsqrtf(var + EPS);
  }
  __syncthreads();
  const float mean = stat[0], inv = stat[1];
  float ga[8], be[8];
#pragma unroll
  for (int c = 0; c < 8; ++c) {
    ga[c] = gw[g * 8 + c] * inv;
    be[c] = gb[g * 8 + c] - mean * ga[c];
  }
  for (int lc = 0; lc < NL; lc += 256) {
    const int l = lc + threadIdx.x;
    u16 o[8];
#pragma unroll
    for (int c = 0; c < 8; ++c)
      o[c] = f2bf(fmaxf(fmaf(xp[(size_t)c * NL + l], ga[c], be[c]), 0.f));
    *(bf16x8*)(outT + ((size_t)b * TROWS + 1 + l) * 256 + g * 8) = *(bf16x8*)o;
  }
  if (threadIdx.x < 2) {
    bf16x8 z = (bf16x8){0,0,0,0,0,0,0,0};
    *(bf16x8*)(outT + ((size_t)b * TROWS + (threadIdx.x ? 2049 : 0)) * 256 + g * 8) = z;
  }
}

// ---------------- GroupNorm+ReLU: bf16 T -> bf16 T padded ----
__global__ __launch_bounds__(256)
void gn_T_T(const u16* __restrict__ inT, const float* __restrict__ gw,
            const float* __restrict__ gb, u16* __restrict__ outT)
{
  const int b = blockIdx.x >> 5, g = blockIdx.x & 31;
  const u16* ip = inT + ((size_t)b * TROWS + 1) * 256 + g * 8;
  float s = 0.f, ss = 0.f;
  for (int l = threadIdx.x; l < NL; l += 256) {
    bf16x8 h = *(const bf16x8*)(ip + (size_t)l * 256);
#pragma unroll
    for (int c = 0; c < 8; ++c) {
      const float v = bf2f(((u16*)&h)[c]);
      s += v; ss += v * v;
    }
  }
#pragma unroll
  for (int o = 32; o > 0; o >>= 1) { s += __shfl_down(s, o); ss += __shfl_down(ss, o); }
  __shared__ float rs[4], rss[4], stat[2];
  if ((threadIdx.x & 63) == 0) { rs[threadIdx.x >> 6] = s; rss[threadIdx.x >> 6] = ss; }
  __syncthreads();
  if (threadIdx.x == 0) {
    float S = rs[0] + rs[1] + rs[2] + rs[3];
    float SS = rss[0] + rss[1] + rss[2] + rss[3];
    float mean = S * (1.f / GN_N);
    float var = SS * (1.f / GN_N) - mean * mean;
    stat[0] = mean; stat[1] = rsqrtf(var + EPS);
  }
  __syncthreads();
  const float mean = stat[0], inv = stat[1];
  float ga[8], be[8];
#pragma unroll
  for (int c = 0; c < 8; ++c) {
    ga[c] = gw[g * 8 + c] * inv;
    be[c] = gb[g * 8 + c] - mean * ga[c];
  }
  u16* op = outT + ((size_t)b * TROWS + 1) * 256 + g * 8;
  for (int l = threadIdx.x; l < NL; l += 256) {
    bf16x8 h = *(const bf16x8*)(ip + (size_t)l * 256);
    u16 o[8];
#pragma unroll
    for (int c = 0; c < 8; ++c)
      o[c] = f2bf(fmaxf(fmaf(bf2f(((u16*)&h)[c]), ga[c], be[c]), 0.f));
    *(bf16x8*)(op + (size_t)l * 256) = *(bf16x8*)o;
  }
  if (threadIdx.x < 2) {
    bf16x8 z = (bf16x8){0,0,0,0,0,0,0,0};
    *(bf16x8*)(outT + ((size_t)b * TROWS + (threadIdx.x ? 2049 : 0)) * 256 + g * 8) = z;
  }
}

// ---------------- conv GEMM via MFMA ----------------
// RESM 0: plain bf16 T out (or kq/vT split for OCT=768)
// RESM 1: bf16 T out = conv + resf (fp32 C,L)         [res1: x1T = conv2 + x]
// RESM 2: fp32 (C,L) out = conv + resf                [res2 final: out = conv2 + av]
template<int OCT, int KD, bool HAS_T, int RESM>
__global__ __launch_bounds__(256, 2)
void conv_mfma(const u16* __restrict__ xT, const u16* __restrict__ Wp,
               const float* __restrict__ bias, const float* __restrict__ tadd,
               u16* __restrict__ outT, u16* __restrict__ vTout,
               const float* __restrict__ resf, float* __restrict__ outf)
{
  constexpr int DOFF = (KD == 3) ? 0 : 1;
  __shared__ u16 xs[2][130 * 128];
  const int lb = blockIdx.x * 128;
  const int ocb = blockIdx.y * 128;
  const int b = blockIdx.z;
  const int tid = threadIdx.x;
  const int w = tid >> 6, lane = tid & 63;
  const int l15 = lane & 15, lg = lane >> 4;
  const int woc = (w >> 1) * 64, wl = (w & 1) * 64;

  f32x4 acc[4][4];
#pragma unroll
  for (int i = 0; i < 4; ++i)
#pragma unroll
    for (int j = 0; j < 4; ++j) acc[i][j] = (f32x4){0.f, 0.f, 0.f, 0.f};

  const u16* xTb = xT + ((size_t)b * TROWS + lb) * 256;

  auto stageX = [&](int buf, int ich) {
    u16* xb = &xs[buf][0];
#pragma unroll
    for (int j = 0; j < 8; ++j) {
      const int slot = w * 512 + j * 64 + lane;
      const int row = slot >> 4, g0 = slot & 15;
      const int g = (g0 & 8) | ((g0 ^ row) & 7);
      gld16(xTb + (size_t)row * 256 + ich * 128 + g * 8, xb + (size_t)(w * 512 + j * 64) * 8);
    }
    if (w == 0 && lane < 32) {
      const int slot = 2048 + lane;
      const int row = slot >> 4, g0 = slot & 15;
      const int g = (g0 & 8) | ((g0 ^ row) & 7);
      gld16(xTb + (size_t)row * 256 + ich * 128 + g * 8, xb + (size_t)2048 * 8);
    }
  };
  auto loadW = [&](bf16x8 (&af)[KD][4], int p) {
    const int ich = p >> 2, kc = p & 3;
#pragma unroll
    for (int d = 0; d < KD; ++d)
#pragma unroll
      for (int mf = 0; mf < 4; ++mf)
        af[d][mf] = *(const bf16x8*)(Wp + ((size_t)d * OCT + ocb + woc + mf * 16 + l15) * 256
                                        + ich * 128 + kc * 32 + lg * 8);
  };

  bf16x8 afbuf[2][KD][4];
  stageX(0, 0);
  loadW(afbuf[0], 0);
  __syncthreads();
  stageX(1, 1);

#pragma unroll
  for (int p = 0; p < 8; ++p) {
    if (p == 4) __syncthreads();
    if (p < 7) loadW(afbuf[(p + 1) & 1], p + 1);
    const int kc = p & 3;
    const int gg = kc * 4 + lg;
    const char* xb = (const char*)&xs[p >> 2][0];
#pragma unroll
    for (int nf = 0; nf < 4; ++nf) {
#pragma unroll
      for (int d = 0; d < KD; ++d) {
        const int r = wl + nf * 16 + l15 + d + DOFF;
        const int gsr = (gg & 8) | ((gg ^ r) & 7);
        const bf16x8 bf = *(const bf16x8*)(xb + r * 256 + gsr * 16);
#pragma unroll
        for (int mf = 0; mf < 4; ++mf)
          acc[mf][nf] = __builtin_amdgcn_mfma_f32_16x16x32_bf16(afbuf[p & 1][d][mf], bf, acc[mf][nf], 0, 0, 0);
      }
    }
  }
#pragma unroll
  for (int mf = 0; mf < 4; ++mf) {
    const int ocbase = ocb + woc + mf * 16 + lg * 4;
    float4 bv = *(const float4*)&bias[ocbase];
    if (HAS_T) {
      const float4 tv = *(const float4*)&tadd[b * 256 + ocbase];
      bv.x += tv.x; bv.y += tv.y; bv.z += tv.z; bv.w += tv.w;
    }
#pragma unroll
    for (int nf = 0; nf < 4; ++nf) {
      const int l = lb + wl + nf * 16 + l15;
      const f32x4 a = acc[mf][nf];
      float v0 = a[0] + bv.x, v1 = a[1] + bv.y, v2 = a[2] + bv.z, v3 = a[3] + bv.w;
      if (RESM >= 1) {
        const float* rp = resf + ((size_t)b * NC + ocbase) * NL + l;
        v0 += rp[0]; v1 += rp[NL]; v2 += rp[2 * (size_t)NL]; v3 += rp[3 * (size_t)NL];
      }
      if (RESM == 2) {
        float* op = outf + ((size_t)b * NC + ocbase) * NL + l;
        op[0] = v0; op[NL] = v1; op[2 * (size_t)NL] = v2; op[3 * (size_t)NL] = v3;
      } else if (OCT == 256) {
        ushort4 st = {f2bf(v0), f2bf(v1), f2bf(v2), f2bf(v3)};
        *(ushort4*)(outT + ((size_t)b * TROWS + 1 + l) * 256 + ocbase) = st;
      } else {
        if (ocb + woc < 512) {
          ushort4 st = {f2bf(v0), f2bf(v1), f2bf(v2), f2bf(v3)};
          *(ushort4*)(outT + ((size_t)b * NL + l) * 512 + ocbase) = st;
        } else {
          const int cv = ocbase - 512;
          vTout[((size_t)b * NC + cv + 0) * NL + l] = f2bf(v0);
          vTout[((size_t)b * NC + cv + 1) * NL + l] = f2bf(v1);
          vTout[((size_t)b * NC + cv + 2) * NL + l] = f2bf(v2);
          vTout[((size_t)b * NC + cv + 3) * NL + l] = f2bf(v3);
        }
      }
    }
  }
}

// ---------------- flash attention: split-KV x2, counted-vmcnt pipeline ----------------
// kq: (B,L,512) bf16 (q log2-scaled); vT: (B,C,L) bf16.
// K LDS: 32 rows x 32 granules, col = (g + r) & 31     -> bank-balanced b128 reads
// V LDS: 256 rows x 4 granules, col = (g + r + (r>>2)) & 3 -> <=2-way (free)
#define AKVB 32
#define ATILES 32    // 1024 kv per half / 32

__global__ __launch_bounds__(256, 2)
void attn_mfma(const u16* __restrict__ kq, const u16* __restrict__ vT,
               u16* __restrict__ part, float2* __restrict__ stats)
{
  __shared__ u16 ks[2][32 * 256];    // 16 KB each
  __shared__ u16 vs[2][256 * 32];    // 16 KB each

  const int fid = blockIdx.x;                 // 512 blocks
  const int xcd = fid & 7, idx = fid >> 3;
  const int b = (xcd << 1) | (idx & 1);
  const int rest = idx >> 1;
  const int qt = rest & 15, half = rest >> 4;
  const int kvbase = half * 1024;

  const int tid = threadIdx.x;
  const int w = tid >> 6, lane = tid & 63;
  const int l31 = lane & 31, lh = lane >> 5;
  const int q = qt * 128 + w * 32 + l31;

  const u16* kqb = kq + (size_t)b * NL * 512;
  const u16* vb  = vT + (size_t)b * NC * NL;

  // 8 gld16 per wave per stage (4 K + 4 V); inverse rotation on the global source
  auto stage = [&](int buf, int kv0) {
#pragma unroll
    for (int j = 0; j < 4; ++j) {
      const int slot = w * 256 + j * 64 + lane;
      const int r = slot >> 5, c = slot & 31;
      const int g = (c - r) & 31;
      gld16(kqb + (size_t)(kv0 + r) * 512 + g * 8, &ks[buf][(size_t)(w * 256 + j * 64) * 8]);
    }
#pragma unroll
    for (int j = 0; j < 4; ++j) {
      const int slot = w * 256 + j * 64 + lane;
      const int r = slot >> 2, c = slot & 3;
      const int g = (c - r - (r >> 2)) & 3;
      gld16(vb + (size_t)r * NL + kv0 + g * 8, &vs[buf][(size_t)(w * 256 + j * 64) * 8]);
    }
  };

  // Q as B-operand: B[k=c][n=q], lane: n=q=l31, k = kk*16 + lh*8 + j
  bf16x8 qf[16];
  {
    const u16* qp = kqb + (size_t)q * 512 + 256 + lh * 8;
#pragma unroll
    for (int kk = 0; kk < 16; ++kk) qf[kk] = *(const bf16x8*)(qp + kk * 16);
  }

  f32x16 o[8];
#pragma unroll
  for (int i = 0; i < 8; ++i)
    o[i] = (f32x16){0.f,0.f,0.f,0.f,0.f,0.f,0.f,0.f,0.f,0.f,0.f,0.f,0.f,0.f,0.f,0.f};
  float m = -1e30f, lsum = 0.f;

  // prologue: 2 tiles in flight; wait only the oldest 8 (tile 0)
  stage(0, kvbase);
  stage(1, kvbase + AKVB);
  asm volatile("s_waitcnt vmcnt(8)" ::: "memory");
  __builtin_amdgcn_sched_barrier(0);
  __builtin_amdgcn_s_barrier();

  for (int t = 0; t < ATILES; ++t) {
    const int cur = t & 1;
    // ---- S = K*Q (swapped): D[m=kv][n=q]; dual acc halves the dep chain ----
    const u16* kbase = &ks[cur][0];
    f32x16 sa = (f32x16){0.f,0.f,0.f,0.f,0.f,0.f,0.f,0.f,0.f,0.f,0.f,0.f,0.f,0.f,0.f,0.f};
    f32x16 sb = sa;
    __builtin_amdgcn_s_setprio(1);
#pragma unroll
    for (int kk = 0; kk < 16; kk += 2) {
      const bf16x8 kfa = *(const bf16x8*)(kbase + l31 * 256 + (((2 * kk + lh) + l31) & 31) * 8);
      sa = __builtin_amdgcn_mfma_f32_32x32x16_bf16(kfa, qf[kk], sa, 0, 0, 0);
      const bf16x8 kfb = *(const bf16x8*)(kbase + l31 * 256 + (((2 * kk + 2 + lh) + l31) & 31) * 8);
      sb = __builtin_amdgcn_mfma_f32_32x32x16_bf16(kfb, qf[kk + 1], sb, 0, 0, 0);
    }
    __builtin_amdgcn_s_setprio(0);
    f32x16 s = sa + sb;
    // ---- in-register online softmax (log2 domain) ----
    float tm = s[0];
#pragma unroll
    for (int i = 1; i < 16; ++i) tm = fmaxf(tm, s[i]);
    tm = fmaxf(tm, __shfl_xor(tm, 32));
    if (!__all(tm <= m + DEFER)) {
      const float mn = fmaxf(m, tm);
      const float corr = ex2(m - mn);
      m = mn; lsum *= corr;
#pragma unroll
      for (int i = 0; i < 8; ++i) o[i] *= corr;
    }
    float sum = 0.f;
#pragma unroll
    for (int i = 0; i < 16; ++i) { s[i] = ex2(s[i] - m); sum += s[i]; }
    sum += __shfl_xor(sum, 32);
    lsum += sum;
    // ---- pack P: cvt_pk + cross-half exchange ----
    u32 pk[8];
#pragma unroll
    for (int i = 0; i < 8; ++i) pk[i] = cvtpk(s[2 * i], s[2 * i + 1]);
    // ---- O += V*P ----
    const u16* vbase = &vs[cur][0];
#pragma unroll
    for (int ksx = 0; ksx < 2; ++ksx) {
      const int base = ksx * 4;
      const u32 send0 = lh ? pk[base + 0] : pk[base + 2];
      const u32 send1 = lh ? pk[base + 1] : pk[base + 3];
      const u32 r0 = (u32)__shfl_xor((int)send0, 32);
      const u32 r1 = (u32)__shfl_xor((int)send1, 32);
      union { u32 wd[4]; bf16x8 v; } pu;
      pu.wd[0] = lh ? r0 : pk[base + 0];
      pu.wd[1] = lh ? r1 : pk[base + 1];
      pu.wd[2] = lh ? pk[base + 2] : r0;
      pu.wd[3] = lh ? pk[base + 3] : r1;
      const bf16x8 pf = pu.v;
      const int gn = 2 * ksx + lh;
      __builtin_amdgcn_s_setprio(1);
#pragma unroll
      for (int mf = 0; mf < 8; ++mf) {
        const int row = mf * 32 + l31;
        const bf16x8 vf = *(const bf16x8*)(vbase + row * 32 + ((gn + row + (row >> 2)) & 3) * 8);
        o[mf] = __builtin_amdgcn_mfma_f32_32x32x16_bf16(vf, pf, o[mf], 0, 0, 0);
      }
      __builtin_amdgcn_s_setprio(0);
    }
    // ---- counted-vmcnt tile boundary: never drain to 0 in-loop ----
    if (t + 1 < ATILES) {
      asm volatile("s_waitcnt lgkmcnt(0)" ::: "memory");
      __builtin_amdgcn_s_barrier();            // all waves done reading buf cur
      if (t + 2 < ATILES) {
        stage(cur, kvbase + (t + 2) * AKVB);   // refill the freed buffer
        asm volatile("s_waitcnt vmcnt(8)" ::: "memory");   // tile t+1 landed; t+2 in flight
      } else {
        asm volatile("s_waitcnt vmcnt(0)" ::: "memory");
      }
      __builtin_amdgcn_sched_barrier(0);
    }
  }
  // ---- store unnormalized partial (bf16) + stats ----
  u16* pp = part + half * PHALF + (size_t)b * NC * NL + q;
#pragma unroll
  for (int mf = 0; mf < 8; ++mf)
#pragma unroll
    for (int r = 0; r < 16; ++r) {
      const int c = mf * 32 + (r & 3) + 8 * (r >> 2) + 4 * lh;
      pp[(size_t)c * NL] = f2bf(o[mf][r]);
    }
  if (lane < 32)
    stats[((size_t)half * NB + b) * NL + q] = make_float2(m, lsum);
}

// ---------------- combine split-KV partials -> av (C,L) fp32 (coalesced) ----------------
__global__ __launch_bounds__(256)
void attn_combine(const u16* __restrict__ part, const float2* __restrict__ stats,
                  float* __restrict__ av)
{
  const int c = blockIdx.x, b = blockIdx.y;
  const u16* p0 = part + ((size_t)b * NC + c) * NL;
  const u16* p1 = p0 + PHALF;
  const float2* s0p = stats + (size_t)b * NL;
  const float2* s1p = stats + ((size_t)NB + b) * NL;
  float* op = av + ((size_t)b * NC + c) * NL;
#pragma unroll
  for (int j = 0; j < 8; ++j) {
    const int l = threadIdx.x + j * 256;
    const float2 a = s0p[l], bb = s1p[l];
    const float M = fmaxf(a.x, bb.x);
    const float e0 = ex2(a.x - M), e1 = ex2(bb.x - M);
    const float den = 1.f / (a.y * e0 + bb.y * e1);
    op[l] = (bf2f(p0[l]) * e0 + bf2f(p1[l]) * e1) * den;
  }
}

extern "C" void kernel_launch(void* const* d_in, const int* in_sizes, int n_in,
                              void* d_out, int out_size, void* d_ws, size_t ws_size,
                              hipStream_t stream)
{
  (void)in_sizes; (void)n_in; (void)out_size; (void)ws_size;
  const float* x        = (const float*)d_in[0];
  const float* t        = (const float*)d_in[1];
  const float* r1_gn1_w = (const float*)d_in[2];
  const float* r1_gn1_b = (const float*)d_in[3];
  const float* r1_c1_w  = (const float*)d_in[4];
  const float* r1_c1_b  = (const float*)d_in[5];
  const float* r1_gn2_w = (const float*)d_in[6];
  const float* r1_gn2_b = (const float*)d_in[7];
  const float* r1_c2_w  = (const float*)d_in[8];
  const float* r1_c2_b  = (const float*)d_in[9];
  const float* r2_gn1_w = (const float*)d_in[10];
  const float* r2_gn1_b = (const float*)d_in[11];
  const float* r2_c1_w  = (const float*)d_in[12];
  const float* r2_c1_b  = (const float*)d_in[13];
  const float* r2_gn2_w = (const float*)d_in[14];
  const float* r2_gn2_b = (const float*)d_in[15];
  const float* r2_c2_w  = (const float*)d_in[16];
  const float* r2_c2_b  = (const float*)d_in[17];
  const float* lin_w    = (const float*)d_in[18];
  const float* lin_b    = (const float*)d_in[19];

  float* out = (float*)d_out;

  // ws: tA [0,TSZ) | tB/kq/avF [TSZ,3TSZ) | tC/vT [3TSZ,4TSZ) | weights
  const size_t TSZ = (size_t)NB * TROWS * 256 * 2;           // 16,793,600
  u16* tA  = (u16*)d_ws;
  u16* tB  = (u16*)((char*)d_ws + TSZ);
  u16* kq  = tB;                                             // (B,2048,512) spans [TSZ,3TSZ)
  float* avF = (float*)((char*)d_ws + TSZ);                  // fp32 av, after kq consumed
  u16* tC  = (u16*)((char*)d_ws + 3 * TSZ);
  u16* vT  = tC;
  u16* Wp  = (u16*)((char*)d_ws + 4 * TSZ);
  u16* Wq  = Wp + 4 * 196608;
  float* bq = (float*)(Wq + 196608);

  const dim3 gPack(768, 5);
  const dim3 gC(16, 2, NB);
  const dim3 gQ(16, 6, NB);
  const dim3 gCmb(NC, NB);

  pack_w<<<gPack, 256, 0, stream>>>(r1_c1_w, r1_c2_w, r2_c1_w, r2_c2_w, lin_w, lin_b, Wp, Wq, bq);

  // res1: gn1(x)->tA; conv1->tB; gn2->tC; conv2+x -> tA (x1T, fused residual)
  gn_f32_T<<<NB * NG, 256, 0, stream>>>(x, r1_gn1_w, r1_gn1_b, tA);
  conv_mfma<256, 3, true, 0><<<gC, 256, 0, stream>>>(tA, Wp, r1_c1_b, t, tB, nullptr, nullptr, nullptr);
  gn_T_T<<<NB * NG, 256, 0, stream>>>(tB, r1_gn2_w, r1_gn2_b, tC);
  conv_mfma<256, 3, false, 1><<<gC, 256, 0, stream>>>(tC, Wp + 196608, r1_c2_b, nullptr, tA, nullptr, x, nullptr);

  // attention: qkv(tA) -> kq(tB span) + vT(tC); partials -> d_out; combine -> avF
  conv_mfma<768, 1, false, 0><<<gQ, 256, 0, stream>>>(tA, Wq, bq, nullptr, kq, vT, nullptr, nullptr);
  attn_mfma<<<512, 256, 0, stream>>>(kq, vT, (u16*)out, (float2*)tA);
  attn_combine<<<gCmb, 256, 0, stream>>>((const u16*)out, (const float2*)tA, avF);

  // res2: gn1'(avF)->tA; conv1'->tC; gn2'->tA; conv2'+avF -> d_out fp32 (fused)
  gn_f32_T<<<NB * NG, 256, 0, stream>>>(avF, r2_gn1_w, r2_gn1_b, tA);
  conv_mfma<256, 3, true, 0><<<gC, 256, 0, stream>>>(tA, Wp + 2 * 196608, r2_c1_b, t, tC, nullptr, nullptr, nullptr);
  gn_T_T<<<NB * NG, 256, 0, stream>>>(tC, r2_gn2_w, r2_gn2_b, tA);
  conv_mfma<256, 3, false, 2><<<gC, 256, 0, stream>>>(tA, Wp + 3 * 196608, r2_c2_b, nullptr, nullptr, nullptr, avF, out);
}

// Round 9
// 368.060 us; speedup vs baseline: 1.3021x; 1.3021x over previous
//
#include <hip/hip_runtime.h>

typedef unsigned short u16;
typedef unsigned int u32;
typedef __attribute__((ext_vector_type(8))) short bf16x8;
typedef __attribute__((ext_vector_type(4))) float f32x4;
typedef __attribute__((ext_vector_type(16))) float f32x16;

#define NB 16
#define NC 256
#define NL 2048
#define NG 32
#define EPS 1e-5f
#define QSC2 0.0901684401f   // (1/sqrt(256)) * log2(e)
#define DEFER 11.54f         // 8 * log2(e)
#define TROWS 2050
#define PHALF ((size_t)NB * NC * NL)

__device__ __forceinline__ float bf2f(u16 a) {
  union { unsigned u; float f; } v; v.u = (unsigned)a << 16; return v.f;
}
__device__ __forceinline__ u16 f2bf(float f) {
  union { float f; unsigned u; } v; v.f = f;
  return (u16)((v.u + 0x7fffu + ((v.u >> 16) & 1u)) >> 16);
}
__device__ __forceinline__ u32 cvtpk(float lo, float hi) {
  u32 r;
  asm("v_cvt_pk_bf16_f32 %0, %1, %2" : "=v"(r) : "v"(lo), "v"(hi));
  return r;
}
__device__ __forceinline__ float ex2(float x) {
  float r;
  asm("v_exp_f32 %0, %1" : "=v"(r) : "v"(x));
  return r;
}
__device__ __forceinline__ void gld16(const void* gsrc, void* ldst) {
  __builtin_amdgcn_global_load_lds(
      (const __attribute__((address_space(1))) void*)gsrc,
      (__attribute__((address_space(3))) void*)ldst, 16, 0, 0);
}

// ---------------- weight pack ----------------
__global__ __launch_bounds__(256)
void pack_w(const float* __restrict__ w1, const float* __restrict__ w2,
            const float* __restrict__ w3, const float* __restrict__ w4,
            const float* __restrict__ lw, const float* __restrict__ lb,
            u16* __restrict__ Wp, u16* __restrict__ Wq, float* __restrict__ bq)
{
  const int a = blockIdx.y;
  const int gid = blockIdx.x * 256 + threadIdx.x;
  if (a < 4) {
    const float* w = a == 0 ? w1 : a == 1 ? w2 : a == 2 ? w3 : w4;
    const int d = gid >> 16, rem = gid & 65535;
    const int oc = rem >> 8, ic = rem & 255;
    Wp[a * 196608 + gid] = f2bf(w[(oc * 256 + ic) * 3 + d]);
  } else {
    const int oc = gid >> 8;
    const float s = (oc >= 256 && oc < 512) ? QSC2 : 1.0f;
    Wq[gid] = f2bf(lw[gid] * s);
    if (gid < 768) bq[gid] = lb[gid] * ((gid >= 256 && gid < 512) ? QSC2 : 1.0f);
  }
}

// ---------------- GN stats: fp32 (C,L), one block per (b,c) -> pstat[b*256+c] ----
__global__ __launch_bounds__(256)
void stats_f32(const float* __restrict__ x, float2* __restrict__ pstat)
{
  const int blk = blockIdx.x;
  const float* p = x + (size_t)blk * NL + threadIdx.x * 8;
  const float4 a = ((const float4*)p)[0];
  const float4 c4 = ((const float4*)p)[1];
  float s = (a.x + a.y) + (a.z + a.w) + (c4.x + c4.y) + (c4.z + c4.w);
  float ss = a.x*a.x + a.y*a.y + a.z*a.z + a.w*a.w + c4.x*c4.x + c4.y*c4.y + c4.z*c4.z + c4.w*c4.w;
#pragma unroll
  for (int o = 32; o > 0; o >>= 1) { s += __shfl_down(s, o); ss += __shfl_down(ss, o); }
  __shared__ float2 red[4];
  if ((threadIdx.x & 63) == 0) red[threadIdx.x >> 6] = make_float2(s, ss);
  __syncthreads();
  if (threadIdx.x == 0)
    pstat[blk] = make_float2(red[0].x + red[1].x + red[2].x + red[3].x,
                             red[0].y + red[1].y + red[2].y + red[3].y);
}

// ---------------- GN stats: bf16 T layout, 16 partial chunks -> pstat[(b*16+chunk)*256+c] ----
__global__ __launch_bounds__(256)
void stats_T(const u16* __restrict__ inT, float2* __restrict__ pstat)
{
  const int chunk = blockIdx.x, b = blockIdx.y;
  const int t = threadIdx.x;
  const int c4 = (t & 63) * 4;
  float s[4] = {0.f, 0.f, 0.f, 0.f}, ss[4] = {0.f, 0.f, 0.f, 0.f};
  for (int j = 0; j < 32; ++j) {
    const int row = chunk * 128 + j * 4 + (t >> 6);
    const ushort4 h = *(const ushort4*)(inT + ((size_t)b * TROWS + 1 + row) * 256 + c4);
    const float v0 = bf2f(h.x), v1 = bf2f(h.y), v2 = bf2f(h.z), v3 = bf2f(h.w);
    s[0] += v0; ss[0] += v0 * v0;
    s[1] += v1; ss[1] += v1 * v1;
    s[2] += v2; ss[2] += v2 * v2;
    s[3] += v3; ss[3] += v3 * v3;
  }
  __shared__ float2 srs[256][4];
#pragma unroll
  for (int i = 0; i < 4; ++i) srs[t][i] = make_float2(s[i], ss[i]);
  __syncthreads();
  if (t < 64) {
#pragma unroll
    for (int r = 1; r < 4; ++r)
#pragma unroll
      for (int i = 0; i < 4; ++i) {
        s[i] += srs[t + 64 * r][i].x;
        ss[i] += srs[t + 64 * r][i].y;
      }
#pragma unroll
    for (int i = 0; i < 4; ++i)
      pstat[((size_t)b * 16 + chunk) * 256 + t * 4 + i] = make_float2(s[i], ss[i]);
  }
}

// ---------------- GN apply: fp32 (C,L) -> bf16 T padded (transpose, coalesced) ----
__global__ __launch_bounds__(256)
void apply_f32T(const float* __restrict__ x, const float2* __restrict__ pstat,
                const float* __restrict__ gw, const float* __restrict__ gb,
                u16* __restrict__ outT)
{
  __shared__ float2 chs[256];
  __shared__ float gm[32], gi[32];
  __shared__ float ta[256][33];
  const int t = threadIdx.x, b = blockIdx.y;
  const int L0 = blockIdx.x * 32;
  chs[t] = pstat[b * 256 + t];
  __syncthreads();
  if (t < 32) {
    float S = 0.f, SS = 0.f;
#pragma unroll
    for (int j = 0; j < 8; ++j) { S += chs[t * 8 + j].x; SS += chs[t * 8 + j].y; }
    const float mean = S * (1.f / 16384.f);
    const float var = SS * (1.f / 16384.f) - mean * mean;
    gm[t] = mean; gi[t] = rsqrtf(var + EPS);
  }
  const int cR = t >> 3, lq = (t & 7) * 4;
#pragma unroll
  for (int i = 0; i < 8; ++i) {
    const int c = i * 32 + cR;
    const float4 v = *(const float4*)&x[((size_t)b * NC + c) * NL + L0 + lq];
    ta[c][lq] = v.x; ta[c][lq + 1] = v.y; ta[c][lq + 2] = v.z; ta[c][lq + 3] = v.w;
  }
  __syncthreads();
  const int g = t & 31;
  float ga[8], be[8];
#pragma unroll
  for (int j = 0; j < 8; ++j) {
    ga[j] = gw[g * 8 + j] * gi[g];
    be[j] = gb[g * 8 + j] - gm[g] * ga[j];
  }
#pragma unroll
  for (int i = 0; i < 4; ++i) {
    const int chunk = i * 256 + t;
    const int row = chunk >> 5;
    const int ch8 = g * 8;
    u16 o[8];
#pragma unroll
    for (int j = 0; j < 8; ++j)
      o[j] = f2bf(fmaxf(fmaf(ta[ch8 + j][row], ga[j], be[j]), 0.f));
    *(bf16x8*)(outT + ((size_t)b * TROWS + 1 + L0 + row) * 256 + ch8) = *(bf16x8*)o;
  }
  if (blockIdx.x == 0 && t < 128) {
    const int r = (t >> 6) ? 2049 : 0;
    *(ushort4*)(outT + ((size_t)b * TROWS + r) * 256 + (t & 63) * 4) = (ushort4){0, 0, 0, 0};
  }
}

// ---------------- GN apply: bf16 T -> bf16 T padded (coalesced, in!=out) ----
__global__ __launch_bounds__(256)
void apply_TT(const u16* __restrict__ inT, const float2* __restrict__ pstat,
              const float* __restrict__ gw, const float* __restrict__ gb,
              u16* __restrict__ outT)
{
  __shared__ float2 chs[256];
  __shared__ float gm[32], gi[32];
  const int t = threadIdx.x, b = blockIdx.y;
  {
    float S = 0.f, SS = 0.f;
#pragma unroll
    for (int p = 0; p < 16; ++p) {
      const float2 v = pstat[((size_t)b * 16 + p) * 256 + t];
      S += v.x; SS += v.y;
    }
    chs[t] = make_float2(S, SS);
  }
  __syncthreads();
  if (t < 32) {
    float S = 0.f, SS = 0.f;
#pragma unroll
    for (int j = 0; j < 8; ++j) { S += chs[t * 8 + j].x; SS += chs[t * 8 + j].y; }
    const float mean = S * (1.f / 16384.f);
    const float var = SS * (1.f / 16384.f) - mean * mean;
    gm[t] = mean; gi[t] = rsqrtf(var + EPS);
  }
  __syncthreads();
  const int g = t & 31;
  float ga[8], be[8];
#pragma unroll
  for (int j = 0; j < 8; ++j) {
    ga[j] = gw[g * 8 + j] * gi[g];
    be[j] = gb[g * 8 + j] - gm[g] * ga[j];
  }
#pragma unroll
  for (int j = 0; j < 16; ++j) {
    const int row = blockIdx.x * 128 + j * 8 + (t >> 5);
    const size_t off = ((size_t)b * TROWS + 1 + row) * 256 + g * 8;
    const bf16x8 h = *(const bf16x8*)(inT + off);
    u16 o[8];
#pragma unroll
    for (int i = 0; i < 8; ++i)
      o[i] = f2bf(fmaxf(fmaf(bf2f(((const u16*)&h)[i]), ga[i], be[i]), 0.f));
    *(bf16x8*)(outT + off) = *(bf16x8*)o;
  }
  if (blockIdx.x == 0 && t < 128) {
    const int r = (t >> 6) ? 2049 : 0;
    *(ushort4*)(outT + ((size_t)b * TROWS + r) * 256 + (t & 63) * 4) = (ushort4){0, 0, 0, 0};
  }
}

// ---------------- conv GEMM via MFMA (DMA-staged x, W prefetch, v-tile transpose) ----
// RESM 0: bf16 T out (or kq/vT for OCT=768); RESM 1: bf16 T = conv+resf; RESM 2: fp32 = conv+resf
template<int OCT, int KD, bool HAS_T, int RESM>
__global__ __launch_bounds__(256, 2)
void conv_mfma(const u16* __restrict__ xT, const u16* __restrict__ Wp,
               const float* __restrict__ bias, const float* __restrict__ tadd,
               u16* __restrict__ outT, u16* __restrict__ vTout,
               const float* __restrict__ resf, float* __restrict__ outf)
{
  constexpr int DOFF = (KD == 3) ? 0 : 1;
  __shared__ __align__(16) u16 xs[2][130 * 128];
  const int lb = blockIdx.x * 128;
  const int ocb = blockIdx.y * 128;
  const int b = blockIdx.z;
  const int tid = threadIdx.x;
  const int w = tid >> 6, lane = tid & 63;
  const int l15 = lane & 15, lg = lane >> 4;
  const int woc = (w >> 1) * 64, wl = (w & 1) * 64;

  f32x4 acc[4][4];
#pragma unroll
  for (int i = 0; i < 4; ++i)
#pragma unroll
    for (int j = 0; j < 4; ++j) acc[i][j] = (f32x4){0.f, 0.f, 0.f, 0.f};

  const u16* xTb = xT + ((size_t)b * TROWS + lb) * 256;

  auto stageX = [&](int buf, int ich) {
    u16* xb = &xs[buf][0];
#pragma unroll
    for (int j = 0; j < 8; ++j) {
      const int slot = w * 512 + j * 64 + lane;
      const int row = slot >> 4, g0 = slot & 15;
      const int g = (g0 & 8) | ((g0 ^ row) & 7);
      gld16(xTb + (size_t)row * 256 + ich * 128 + g * 8, xb + (size_t)(w * 512 + j * 64) * 8);
    }
    if (w == 0 && lane < 32) {
      const int slot = 2048 + lane;
      const int row = slot >> 4, g0 = slot & 15;
      const int g = (g0 & 8) | ((g0 ^ row) & 7);
      gld16(xTb + (size_t)row * 256 + ich * 128 + g * 8, xb + (size_t)2048 * 8);
    }
  };
  auto loadW = [&](bf16x8 (&af)[KD][4], int p) {
    const int ich = p >> 2, kc = p & 3;
#pragma unroll
    for (int d = 0; d < KD; ++d)
#pragma unroll
      for (int mf = 0; mf < 4; ++mf)
        af[d][mf] = *(const bf16x8*)(Wp + ((size_t)d * OCT + ocb + woc + mf * 16 + l15) * 256
                                        + ich * 128 + kc * 32 + lg * 8);
  };

  bf16x8 afbuf[2][KD][4];
  stageX(0, 0);
  loadW(afbuf[0], 0);
  __syncthreads();
  stageX(1, 1);

#pragma unroll
  for (int p = 0; p < 8; ++p) {
    if (p == 4) __syncthreads();
    if (p < 7) loadW(afbuf[(p + 1) & 1], p + 1);
    const int kc = p & 3;
    const int gg = kc * 4 + lg;
    const char* xb = (const char*)&xs[p >> 2][0];
#pragma unroll
    for (int nf = 0; nf < 4; ++nf) {
#pragma unroll
      for (int d = 0; d < KD; ++d) {
        const int r = wl + nf * 16 + l15 + d + DOFF;
        const int gsr = (gg & 8) | ((gg ^ r) & 7);
        const bf16x8 bf = *(const bf16x8*)(xb + r * 256 + gsr * 16);
#pragma unroll
        for (int mf = 0; mf < 4; ++mf)
          acc[mf][nf] = __builtin_amdgcn_mfma_f32_16x16x32_bf16(afbuf[p & 1][d][mf], bf, acc[mf][nf], 0, 0, 0);
      }
    }
  }

  if (OCT == 768 && ocb >= 512) {
    // v-block: LDS transpose -> coalesced (C,L) bf16 writes
    __syncthreads();
    u16* tile = (u16*)&xs[0][0];   // [128][136]
#pragma unroll
    for (int mf = 0; mf < 4; ++mf) {
      const int cl = woc + mf * 16 + lg * 4;
      const float4 bv = *(const float4*)&bias[ocb + cl];
#pragma unroll
      for (int nf = 0; nf < 4; ++nf) {
        const int ll = wl + nf * 16 + l15;
        const f32x4 a = acc[mf][nf];
        tile[(cl + 0) * 136 + ll] = f2bf(a[0] + bv.x);
        tile[(cl + 1) * 136 + ll] = f2bf(a[1] + bv.y);
        tile[(cl + 2) * 136 + ll] = f2bf(a[2] + bv.z);
        tile[(cl + 3) * 136 + ll] = f2bf(a[3] + bv.w);
      }
    }
    __syncthreads();
    const int cv0 = ocb - 512;
#pragma unroll
    for (int it = 0; it < 8; ++it) {
      const int chunk = it * 256 + tid;
      const int row = chunk >> 4, off = (chunk & 15) * 8;
      const bf16x8 v = *(const bf16x8*)&tile[row * 136 + off];
      *(bf16x8*)(vTout + ((size_t)b * NC + cv0 + row) * NL + lb + off) = v;
    }
    return;
  }

#pragma unroll
  for (int mf = 0; mf < 4; ++mf) {
    const int ocbase = ocb + woc + mf * 16 + lg * 4;
    float4 bv = *(const float4*)&bias[ocbase];
    if (HAS_T) {
      const float4 tv = *(const float4*)&tadd[b * 256 + ocbase];
      bv.x += tv.x; bv.y += tv.y; bv.z += tv.z; bv.w += tv.w;
    }
#pragma unroll
    for (int nf = 0; nf < 4; ++nf) {
      const int l = lb + wl + nf * 16 + l15;
      const f32x4 a = acc[mf][nf];
      float v0 = a[0] + bv.x, v1 = a[1] + bv.y, v2 = a[2] + bv.z, v3 = a[3] + bv.w;
      if (RESM >= 1) {
        const float* rp = resf + ((size_t)b * NC + ocbase) * NL + l;
        v0 += rp[0]; v1 += rp[NL]; v2 += rp[2 * (size_t)NL]; v3 += rp[3 * (size_t)NL];
      }
      if (RESM == 2) {
        float* op = outf + ((size_t)b * NC + ocbase) * NL + l;
        op[0] = v0; op[NL] = v1; op[2 * (size_t)NL] = v2; op[3 * (size_t)NL] = v3;
      } else if (OCT == 256) {
        ushort4 st = {f2bf(v0), f2bf(v1), f2bf(v2), f2bf(v3)};
        *(ushort4*)(outT + ((size_t)b * TROWS + 1 + l) * 256 + ocbase) = st;
      } else {
        ushort4 st = {f2bf(v0), f2bf(v1), f2bf(v2), f2bf(v3)};
        *(ushort4*)(outT + ((size_t)b * NL + l) * 512 + ocbase) = st;
      }
    }
  }
}

// ---------------- flash attention: split-KV x2, r7 flow + rotation swizzle ----------------
#define AKVB 32
#define ATILES 32

__global__ __launch_bounds__(256, 2)
void attn_mfma(const u16* __restrict__ kq, const u16* __restrict__ vT,
               u16* __restrict__ part, float2* __restrict__ stats)
{
  __shared__ u16 ks[2][32 * 256];
  __shared__ u16 vs[2][256 * 32];

  const int fid = blockIdx.x;
  const int xcd = fid & 7, idx = fid >> 3;
  const int b = (xcd << 1) | (idx & 1);
  const int rest = idx >> 1;
  const int qt = rest & 15, half = rest >> 4;
  const int kvbase = half * 1024;

  const int tid = threadIdx.x;
  const int w = tid >> 6, lane = tid & 63;
  const int l31 = lane & 31, lh = lane >> 5;
  const int q = qt * 128 + w * 32 + l31;

  const u16* kqb = kq + (size_t)b * NL * 512;
  const u16* vb  = vT + (size_t)b * NC * NL;

  // rotation swizzle (bank-conflict-free, measured 0 in r8):
  // K LDS col c holds source granule (c-r)&31; V col c holds (c-r-(r>>2))&3
  auto stage = [&](int buf, int kv0) {
#pragma unroll
    for (int j = 0; j < 4; ++j) {
      const int slot = w * 256 + j * 64 + lane;
      const int r = slot >> 5, c = slot & 31;
      const int g = (c - r) & 31;
      gld16(kqb + (size_t)(kv0 + r) * 512 + g * 8, &ks[buf][(size_t)(w * 256 + j * 64) * 8]);
    }
#pragma unroll
    for (int j = 0; j < 4; ++j) {
      const int slot = w * 256 + j * 64 + lane;
      const int r = slot >> 2, c = slot & 3;
      const int g = (c - r - (r >> 2)) & 3;
      gld16(vb + (size_t)r * NL + kv0 + g * 8, &vs[buf][(size_t)(w * 256 + j * 64) * 8]);
    }
  };

  bf16x8 qf[16];
  {
    const u16* qp = kqb + (size_t)q * 512 + 256 + lh * 8;
#pragma unroll
    for (int kk = 0; kk < 16; ++kk) qf[kk] = *(const bf16x8*)(qp + kk * 16);
  }

  f32x16 o[8];
#pragma unroll
  for (int i = 0; i < 8; ++i)
    o[i] = (f32x16){0.f,0.f,0.f,0.f,0.f,0.f,0.f,0.f,0.f,0.f,0.f,0.f,0.f,0.f,0.f,0.f};
  float m = -1e30f, lsum = 0.f;

  stage(0, kvbase);
  __syncthreads();

  for (int t = 0; t < ATILES; ++t) {
    const int cur = t & 1;
    if (t + 1 < ATILES) stage(cur ^ 1, kvbase + (t + 1) * AKVB);
    // ---- S = K*Q (swapped): D[m=kv][n=q] ----
    const u16* kbase = &ks[cur][0];
    f32x16 s = (f32x16){0.f,0.f,0.f,0.f,0.f,0.f,0.f,0.f,0.f,0.f,0.f,0.f,0.f,0.f,0.f,0.f};
#pragma unroll
    for (int kk = 0; kk < 16; ++kk) {
      const int gn = 2 * kk + lh;
      const bf16x8 kf = *(const bf16x8*)(kbase + (l31 * 32 + ((gn + l31) & 31)) * 8);
      s = __builtin_amdgcn_mfma_f32_32x32x16_bf16(kf, qf[kk], s, 0, 0, 0);
    }
    // ---- in-register online softmax (log2 domain) ----
    float tm = s[0];
#pragma unroll
    for (int i = 1; i < 16; ++i) tm = fmaxf(tm, s[i]);
    tm = fmaxf(tm, __shfl_xor(tm, 32));
    if (!__all(tm <= m + DEFER)) {
      const float mn = fmaxf(m, tm);
      const float corr = ex2(m - mn);
      m = mn; lsum *= corr;
#pragma unroll
      for (int i = 0; i < 8; ++i) o[i] *= corr;
    }
    float sum = 0.f;
#pragma unroll
    for (int i = 0; i < 16; ++i) { s[i] = ex2(s[i] - m); sum += s[i]; }
    sum += __shfl_xor(sum, 32);
    lsum += sum;
    // ---- pack P ----
    u32 pk[8];
#pragma unroll
    for (int i = 0; i < 8; ++i) pk[i] = cvtpk(s[2 * i], s[2 * i + 1]);
    // ---- O += V*P ----
    const u16* vbase = &vs[cur][0];
#pragma unroll
    for (int ksx = 0; ksx < 2; ++ksx) {
      const int base = ksx * 4;
      const u32 send0 = lh ? pk[base + 0] : pk[base + 2];
      const u32 send1 = lh ? pk[base + 1] : pk[base + 3];
      const u32 r0 = (u32)__shfl_xor((int)send0, 32);
      const u32 r1 = (u32)__shfl_xor((int)send1, 32);
      union { u32 wd[4]; bf16x8 v; } pu;
      pu.wd[0] = lh ? r0 : pk[base + 0];
      pu.wd[1] = lh ? r1 : pk[base + 1];
      pu.wd[2] = lh ? pk[base + 2] : r0;
      pu.wd[3] = lh ? pk[base + 3] : r1;
      const bf16x8 pf = pu.v;
      const int gn = 2 * ksx + lh;
#pragma unroll
      for (int mf = 0; mf < 8; ++mf) {
        const int row = mf * 32 + l31;
        const bf16x8 vf = *(const bf16x8*)(vbase + (row * 4 + ((gn + row + (row >> 2)) & 3)) * 8);
        o[mf] = __builtin_amdgcn_mfma_f32_32x32x16_bf16(vf, pf, o[mf], 0, 0, 0);
      }
    }
    if (t + 1 < ATILES) __syncthreads();
  }
  u16* pp = part + half * PHALF + (size_t)b * NC * NL + q;
#pragma unroll
  for (int mf = 0; mf < 8; ++mf)
#pragma unroll
    for (int r = 0; r < 16; ++r) {
      const int c = mf * 32 + (r & 3) + 8 * (r >> 2) + 4 * lh;
      pp[(size_t)c * NL] = f2bf(o[mf][r]);
    }
  if (lane < 32)
    stats[((size_t)half * NB + b) * NL + q] = make_float2(m, lsum);
}

// ---------------- combine split-KV partials -> av fp32, + per-channel GN stats ----------
__global__ __launch_bounds__(256)
void attn_combine(const u16* __restrict__ part, const float2* __restrict__ stats,
                  float* __restrict__ av, float2* __restrict__ pstat)
{
  const int c = blockIdx.x, b = blockIdx.y;
  const u16* p0 = part + ((size_t)b * NC + c) * NL;
  const u16* p1 = p0 + PHALF;
  const float2* s0p = stats + (size_t)b * NL;
  const float2* s1p = stats + ((size_t)NB + b) * NL;
  float* op = av + ((size_t)b * NC + c) * NL;
  float s = 0.f, ss = 0.f;
#pragma unroll
  for (int j = 0; j < 8; ++j) {
    const int l = threadIdx.x + j * 256;
    const float2 a = s0p[l], bb = s1p[l];
    const float M = fmaxf(a.x, bb.x);
    const float e0 = ex2(a.x - M), e1 = ex2(bb.x - M);
    const float den = 1.f / (a.y * e0 + bb.y * e1);
    const float r = (bf2f(p0[l]) * e0 + bf2f(p1[l]) * e1) * den;
    op[l] = r;
    s += r; ss += r * r;
  }
#pragma unroll
  for (int o = 32; o > 0; o >>= 1) { s += __shfl_down(s, o); ss += __shfl_down(ss, o); }
  __shared__ float2 red[4];
  if ((threadIdx.x & 63) == 0) red[threadIdx.x >> 6] = make_float2(s, ss);
  __syncthreads();
  if (threadIdx.x == 0)
    pstat[b * 256 + c] = make_float2(red[0].x + red[1].x + red[2].x + red[3].x,
                                     red[0].y + red[1].y + red[2].y + red[3].y);
}

extern "C" void kernel_launch(void* const* d_in, const int* in_sizes, int n_in,
                              void* d_out, int out_size, void* d_ws, size_t ws_size,
                              hipStream_t stream)
{
  (void)in_sizes; (void)n_in; (void)out_size; (void)ws_size;
  const float* x        = (const float*)d_in[0];
  const float* t        = (const float*)d_in[1];
  const float* r1_gn1_w = (const float*)d_in[2];
  const float* r1_gn1_b = (const float*)d_in[3];
  const float* r1_c1_w  = (const float*)d_in[4];
  const float* r1_c1_b  = (const float*)d_in[5];
  const float* r1_gn2_w = (const float*)d_in[6];
  const float* r1_gn2_b = (const float*)d_in[7];
  const float* r1_c2_w  = (const float*)d_in[8];
  const float* r1_c2_b  = (const float*)d_in[9];
  const float* r2_gn1_w = (const float*)d_in[10];
  const float* r2_gn1_b = (const float*)d_in[11];
  const float* r2_c1_w  = (const float*)d_in[12];
  const float* r2_c1_b  = (const float*)d_in[13];
  const float* r2_gn2_w = (const float*)d_in[14];
  const float* r2_gn2_b = (const float*)d_in[15];
  const float* r2_c2_w  = (const float*)d_in[16];
  const float* r2_c2_b  = (const float*)d_in[17];
  const float* lin_w    = (const float*)d_in[18];
  const float* lin_b    = (const float*)d_in[19];

  float* out = (float*)d_out;

  const size_t TSZ = (size_t)NB * TROWS * 256 * 2;           // 16,793,600
  u16* tA  = (u16*)d_ws;
  u16* tB  = (u16*)((char*)d_ws + TSZ);
  u16* kq  = tB;                                             // spans [TSZ, 3TSZ)
  float* avF = (float*)((char*)d_ws + TSZ);
  u16* tC  = (u16*)((char*)d_ws + 3 * TSZ);
  u16* vT  = tC;
  u16* Wp  = (u16*)((char*)d_ws + 4 * TSZ);
  u16* Wq  = Wp + 4 * 196608;
  float* bq = (float*)(Wq + 196608);
  float2* pstat = (float2*)((char*)bq + 4096);               // 512 KB (16-part max)

  const dim3 gPack(768, 5);
  const dim3 gC(16, 2, NB);
  const dim3 gQ(16, 6, NB);
  const dim3 gS16(16, NB);
  const dim3 gA64(64, NB);
  const dim3 gCmb(NC, NB);

  pack_w<<<gPack, 256, 0, stream>>>(r1_c1_w, r1_c2_w, r2_c1_w, r2_c2_w, lin_w, lin_b, Wp, Wq, bq);

  // res1
  stats_f32<<<NB * NC, 256, 0, stream>>>(x, pstat);
  apply_f32T<<<gA64, 256, 0, stream>>>(x, pstat, r1_gn1_w, r1_gn1_b, tA);
  conv_mfma<256, 3, true, 0><<<gC, 256, 0, stream>>>(tA, Wp, r1_c1_b, t, tB, nullptr, nullptr, nullptr);
  stats_T<<<gS16, 256, 0, stream>>>(tB, pstat);
  apply_TT<<<gS16, 256, 0, stream>>>(tB, pstat, r1_gn2_w, r1_gn2_b, tC);
  conv_mfma<256, 3, false, 1><<<gC, 256, 0, stream>>>(tC, Wp + 196608, r1_c2_b, nullptr, tA, nullptr, x, nullptr);

  // attention
  conv_mfma<768, 1, false, 0><<<gQ, 256, 0, stream>>>(tA, Wq, bq, nullptr, kq, vT, nullptr, nullptr);
  attn_mfma<<<512, 256, 0, stream>>>(kq, vT, (u16*)out, (float2*)tA);
  attn_combine<<<gCmb, 256, 0, stream>>>((const u16*)out, (const float2*)tA, avF, pstat);

  // res2
  apply_f32T<<<gA64, 256, 0, stream>>>(avF, pstat, r2_gn1_w, r2_gn1_b, tA);
  conv_mfma<256, 3, true, 0><<<gC, 256, 0, stream>>>(tA, Wp + 2 * 196608, r2_c1_b, t, tC, nullptr, nullptr, nullptr);
  stats_T<<<gS16, 256, 0, stream>>>(tC, pstat);
  apply_TT<<<gS16, 256, 0, stream>>>(tC, pstat, r2_gn2_w, r2_gn2_b, tA);
  conv_mfma<256, 3, false, 2><<<gC, 256, 0, stream>>>(tA, Wp + 3 * 196608, r2_c2_b, nullptr, nullptr, nullptr, avF, out);
}